// Round 9
// baseline (256.803 us; speedup 1.0000x reference)
//
#include <hip/hip_runtime.h>
#include <stdint.h>

// RNN: h_{t+1} = tanh(x_t @ W_ih^T + b_ih + b_hh + h_t @ W_hh^T), out = h_T @ fc_w^T + fc_b
// B=8192, T=512, IN=8, H=16.
//
// ROUND 9: MFMA OFF the chain (measured: a dependent MFMA segment costs ~250-300
// cyc for a lone wave -> ~370 cyc/step floor in R5-R8). Pure-VALU minimal-depth
// recurrence, assembled from proven pieces:
//  - R1's calibrated DPP row_ror butterfly (16 lanes/elem, all-register gather,
//    depth 4, direction-proof via running the same DPP sequence on lane index j).
//  - R2's algebraic fold: weights pre-scaled by -2c (c = 2*log2 e), rowsum(W_hh)
//    folded into bias, state r = 1/(exp2(S)+1), h = 1-2r deferred (exact f32).
//  - R6's staging: double-buffered global_load_lds; per-tile OFF-CHAIN precompute
//    of the full x-projection xp[tt] = c*(bias+rowsum) + c*W_ih.x_tt (scalar per
//    lane per step -> xp[32] = 32 VGPRs, static indexing, no spill).
// Serial chain per step: butterfly(4) -> FMA(4) -> add(2) -> exp2 -> add -> rcp
// = 13 dependent VALU ops. Everything else (xp, staging) hides in stall slots.
//
// Mapping: 64-thread blocks, 4 elements/wave (16 lanes each), 2048 blocks
// (8 waves/CU = 2/SIMD). f32 state throughout (absmax ~6e-5, no fp16 terms).

#define RNN_B   8192
#define RNN_T   512
#define RNN_IN  8
#define RNN_H   16
#define TC      32                 // timesteps per x tile
#define NE      4                  // batch elements per block (= per wave)
#define XROW    260                // floats per staged row (256 + 4 pad; 1040 B, 16B-aligned)
#define NTILE   (RNN_T / TC)
#define BUFSZ   (NE * XROW)

// DPP row_ror:N within 16-lane rows (CDNA row = 16 lanes). All lanes active.
#if defined(__has_builtin)
#if __has_builtin(__builtin_amdgcn_mov_dpp)
#define ROR16(x, N) ((uint32_t)__builtin_amdgcn_mov_dpp((int)(x), 0x120 + (N), 0xF, 0xF, false))
#endif
#endif
#ifndef ROR16
#define ROR16(x, N) ((uint32_t)__builtin_amdgcn_update_dpp(0, (int)(x), 0x120 + (N), 0xF, 0xF, false))
#endif

// Butterfly all-gather across a 16-lane row: v[m] = value at relative rotation
// offset m. Depth 4. Direction convention calibrated away at init (sv[] below).
__device__ __forceinline__ void gather16(uint32_t in, uint32_t v[16]) {
    v[0]  = in;
    v[8]  = ROR16(v[0], 8);
    v[4]  = ROR16(v[0], 4);
    v[12] = ROR16(v[8], 4);
    v[2]  = ROR16(v[0], 2);
    v[6]  = ROR16(v[4], 2);
    v[10] = ROR16(v[8], 2);
    v[14] = ROR16(v[12], 2);
    v[1]  = ROR16(v[0], 1);
    v[3]  = ROR16(v[2], 1);
    v[5]  = ROR16(v[4], 1);
    v[7]  = ROR16(v[6], 1);
    v[9]  = ROR16(v[8], 1);
    v[11] = ROR16(v[10], 1);
    v[13] = ROR16(v[12], 1);
    v[15] = ROR16(v[14], 1);
}

// Stage one 4-elem x 32-timestep x tile: each row = 256 floats = 1024 B =
// exactly one global_load_lds (64 lanes x 16 B), wave-uniform LDS base per row.
static __device__ __forceinline__ void stage(const float* __restrict__ x,
                                             float* lds_base, int b0, int t0,
                                             int lane)
{
#pragma unroll
    for (int e = 0; e < NE; ++e) {
        const float* gp = x + ((size_t)(b0 + e) * RNN_T + t0) * RNN_IN + lane * 4;
        float* lp = lds_base + e * XROW;
        __builtin_amdgcn_global_load_lds(
            (const __attribute__((address_space(1))) uint32_t*)gp,
            (__attribute__((address_space(3))) uint32_t*)lp,
            16, 0, 0);
    }
}

__global__ __launch_bounds__(64) void rnn_valu_kernel(
    const float* __restrict__ x,     // [B, T, IN]
    const float* __restrict__ W_ih,  // [H, IN]
    const float* __restrict__ W_hh,  // [H, H]
    const float* __restrict__ b_ih,  // [H]
    const float* __restrict__ b_hh,  // [H]
    const float* __restrict__ fc_w,  // [1, H]
    const float* __restrict__ fc_b,  // [1]
    float* __restrict__ out)         // [B, 1]
{
    __shared__ __align__(16) float xs[2 * BUFSZ];   // 8.3 KB double-buffered x

    const int lane = (int)threadIdx.x;   // 0..63
    const int j    = lane & 15;          // hidden unit
    const int g    = lane >> 4;          // element within wave (0..3)
    const int b0   = (int)blockIdx.x * NE;
    const float C2 = 2.8853900817779268f;   // 2*log2(e)

    // --- calibrate the gather: run the identical butterfly on the lane index j;
    // sv[m] = hidden index whose state lands in v[m] on this lane. Pre-permute
    // W_hh row j so whh[m] multiplies v[m]. Direction-proof by construction.
    uint32_t sv[16];
    gather16((uint32_t)j, sv);

    float whh[RNN_H];
    float rsum = 0.0f;
#pragma unroll
    for (int m = 0; m < 16; ++m) {
        const float w = W_hh[j * RNN_H + (int)sv[m]];
        whh[m] = -2.0f * C2 * w;     // multiplies r; h = 1-2r fold
        rsum  += w;
    }
    const float bias_l = C2 * (b_ih[j] + b_hh[j]) + C2 * rsum;

    float wih[RNN_IN];
#pragma unroll
    for (int i = 0; i < RNN_IN; i += 4) {
        const float4 w = *(const float4*)(W_ih + j * RNN_IN + i);
        wih[i] = C2 * w.x; wih[i+1] = C2 * w.y; wih[i+2] = C2 * w.z; wih[i+3] = C2 * w.w;
    }

    // prologue: tile 0 -> buffer 0
    stage(x, xs, b0, 0, lane);
    __syncthreads();

    float rv = 0.5f;   // r-state for h0 = 0

    for (int tile = 0; tile < NTILE; ++tile) {
        const int cur = tile & 1;

        // ---- OFF-CHAIN: x-projection for the whole tile.
        // xp[tt] = bias_l + sum_i wih[i]*x[i]  (scalar per lane; 32 VGPRs).
        // All 16 lanes of a group read the same address -> LDS broadcast.
        // Issued BEFORE next-tile staging so no vmem fence precedes the reads.
        const float* xg = xs + cur * BUFSZ + g * XROW;
        float xp[TC];
#pragma unroll
        for (int tt = 0; tt < TC; ++tt) {
            const float4 xa = *(const float4*)(xg + tt * 8);
            const float4 xb = *(const float4*)(xg + tt * 8 + 4);
            float t0 = fmaf(wih[0], xa.x, bias_l);
            t0 = fmaf(wih[1], xa.y, t0);
            t0 = fmaf(wih[2], xa.z, t0);
            t0 = fmaf(wih[3], xa.w, t0);
            float t1 = wih[4] * xb.x;
            t1 = fmaf(wih[5], xb.y, t1);
            t1 = fmaf(wih[6], xb.z, t1);
            t1 = fmaf(wih[7], xb.w, t1);
            xp[tt] = t0 + t1;
        }

        // issue next tile's async staging; drained by the end-of-tile barrier
        if (tile + 1 < NTILE)
            stage(x, xs + (cur ^ 1) * BUFSZ, b0, (tile + 1) * TC, lane);

        // ---- 32 minimal-chain recurrence steps (pure register VALU work).
        // Chain: butterfly(4) -> FMA(4) -> add(2) -> exp2 -> add -> rcp.
#pragma unroll
        for (int tt = 0; tt < TC; ++tt) {
            uint32_t v[16];
            gather16(__float_as_uint(rv), v);

            // 4 chains of 4, ordered by butterfly-output availability:
            // avail depth: v0:0, v8:1, v4/v12:2, v2/6/10/14:3, odd:4
            float c0 = fmaf(whh[0],  __uint_as_float(v[0]),  xp[tt]);
            c0 = fmaf(whh[8],  __uint_as_float(v[8]),  c0);
            c0 = fmaf(whh[4],  __uint_as_float(v[4]),  c0);
            c0 = fmaf(whh[2],  __uint_as_float(v[2]),  c0);

            float c1 = whh[12] * __uint_as_float(v[12]);
            c1 = fmaf(whh[6],  __uint_as_float(v[6]),  c1);
            c1 = fmaf(whh[10], __uint_as_float(v[10]), c1);
            c1 = fmaf(whh[14], __uint_as_float(v[14]), c1);

            float c2 = whh[1] * __uint_as_float(v[1]);
            c2 = fmaf(whh[3],  __uint_as_float(v[3]),  c2);
            c2 = fmaf(whh[5],  __uint_as_float(v[5]),  c2);
            c2 = fmaf(whh[7],  __uint_as_float(v[7]),  c2);

            float c3 = whh[9] * __uint_as_float(v[9]);
            c3 = fmaf(whh[11], __uint_as_float(v[11]), c3);
            c3 = fmaf(whh[13], __uint_as_float(v[13]), c3);
            c3 = fmaf(whh[15], __uint_as_float(v[15]), c3);

            const float s = (c0 + c1) + (c2 + c3);

            // r = 1/(exp2(S)+1); saturates correctly at +/-inf
            const float e = __builtin_amdgcn_exp2f(s);
            rv = __builtin_amdgcn_rcpf(e + 1.0f);
        }
        __syncthreads();   // drains next-tile staging + fences LDS reuse
    }

    // ---- epilogue: h = 1 - 2r; out[b] = sum_j fc_w[j]*h_j + fc_b
    const float h = fmaf(-2.0f, rv, 1.0f);
    float vsum = h * fc_w[j];
    vsum += __shfl_xor(vsum, 1);
    vsum += __shfl_xor(vsum, 2);
    vsum += __shfl_xor(vsum, 4);
    vsum += __shfl_xor(vsum, 8);
    if (j == 0) out[b0 + g] = vsum + fc_b[0];
}

extern "C" void kernel_launch(void* const* d_in, const int* in_sizes, int n_in,
                              void* d_out, int out_size, void* d_ws, size_t ws_size,
                              hipStream_t stream)
{
    const float* x    = (const float*)d_in[0];
    const float* W_ih = (const float*)d_in[1];
    const float* W_hh = (const float*)d_in[2];
    const float* b_ih = (const float*)d_in[3];
    const float* b_hh = (const float*)d_in[4];
    const float* fc_w = (const float*)d_in[5];
    const float* fc_b = (const float*)d_in[6];
    float* out = (float*)d_out;

    dim3 grid(RNN_B / NE);   // 2048 blocks x 64 threads (8 waves/CU)
    dim3 block(64);
    rnn_valu_kernel<<<grid, block, 0, stream>>>(x, W_ih, W_hh, b_ih, b_hh, fc_w, fc_b, out);
}

// Round 10
// 250.044 us; speedup vs baseline: 1.0270x; 1.0270x over previous
//
#include <hip/hip_runtime.h>
#include <stdint.h>

// RNN: h_{t+1} = tanh(x_t @ W_ih^T + b_ih + b_hh + h_t @ W_hh^T), out = h_T @ fc_w^T + fc_b
// B=8192, T=512, IN=8, H=16.
//
// ROUND 10: VALU scheme was ISSUE-bound (R9: ~98 inst/wave-step measured, 2 waves
// sharing one SIMD issue port -> 570 cyc/step). Halve the instruction count with
// v_dot2_f32_f16 (2 fp16 products + f32 accum per inst):
//  - state h packed to 8 fp16-pairs per step: 1 ror1-DPP + 1 cvt_pkrtz + 7-DPP
//    butterfly (replaces 15-DPP f32 gather).
//  - 8 dot2 (W_hi pairs) replace 16 FMA; 8 MORE dot2 with W_lo residual pairs run
//    as independent chains (issue-only) to compensate fp16 weight rounding.
//  - state rv stays f32; only r's fp16 rounding in products is uncompensated
//    (~2.4e-4/step, feedback gain <0.6 -> absmax ~1e-3).
//  - R2's fold: w = -2c*W_hh (c = 2*log2 e), rowsum folded into bias USING THE
//    SAME (hi+lo) representation; state r = 1/(exp2(S)+1), h = 1-2r deferred.
//  - R9/R6 staging: double-buffered global_load_lds; off-chain f32 xp[32].
//  - PAIR calibration: the identical DPP tree is run at init on j AND ror1(j),
//    giving each packed slot's (lo,hi) source units; weights pre-permuted/packed.
//    Direction/convention-proof by construction.
//
// Mapping: 64-thread blocks, 4 elements/wave (16 lanes each), 2048 blocks
// (2 waves/SIMD). Serial chain/step: ror1 -> pkh -> 3-DPP tree -> 4 dot2 -> add
// -> exp2 -> add -> rcp (~96 cyc); issue ~41 inst/wave-step.

#define RNN_B   8192
#define RNN_T   512
#define RNN_IN  8
#define RNN_H   16
#define TC      32                 // timesteps per x tile
#define NE      4                  // batch elements per block (= per wave)
#define XROW    260                // floats per staged row (256 + 4 pad; 1040 B)
#define NTILE   (RNN_T / TC)
#define BUFSZ   (NE * XROW)

typedef __fp16 half2v __attribute__((ext_vector_type(2)));
union H2U { half2v h; uint32_t u; };

// DPP row_ror:N within 16-lane rows (CDNA row = 16 lanes). All lanes active.
#if defined(__has_builtin)
#if __has_builtin(__builtin_amdgcn_mov_dpp)
#define ROR16(x, N) ((uint32_t)__builtin_amdgcn_mov_dpp((int)(x), 0x120 + (N), 0xF, 0xF, false))
#endif
#endif
#ifndef ROR16
#define ROR16(x, N) ((uint32_t)__builtin_amdgcn_update_dpp(0, (int)(x), 0x120 + (N), 0xF, 0xF, false))
#endif

static __device__ __forceinline__ uint32_t pkh(float a, float b) {
    H2U t; t.h = __builtin_amdgcn_cvt_pkrtz(a, b); return t.u;
}

// dot2: c += a.x*b.x + a.y*b.y  (f32 accumulator, fp16 products)
static __device__ __forceinline__ float fdot2f(uint32_t a, uint32_t b, float c) {
#if defined(__has_builtin) && __has_builtin(__builtin_amdgcn_fdot2)
    H2U x, y; x.u = a; y.u = b;
    return __builtin_amdgcn_fdot2(x.h, y.h, c, false);
#else
    H2U x, y; x.u = a; y.u = b;
    return fmaf((float)x.h[0], (float)y.h[0], fmaf((float)x.h[1], (float)y.h[1], c));
#endif
}

// Stage one 4-elem x 32-timestep x tile: each row = 256 floats = 1024 B =
// exactly one global_load_lds (64 lanes x 16 B), wave-uniform LDS base per row.
static __device__ __forceinline__ void stage(const float* __restrict__ x,
                                             float* lds_base, int b0, int t0,
                                             int lane)
{
#pragma unroll
    for (int e = 0; e < NE; ++e) {
        const float* gp = x + ((size_t)(b0 + e) * RNN_T + t0) * RNN_IN + lane * 4;
        float* lp = lds_base + e * XROW;
        __builtin_amdgcn_global_load_lds(
            (const __attribute__((address_space(1))) uint32_t*)gp,
            (__attribute__((address_space(3))) uint32_t*)lp,
            16, 0, 0);
    }
}

__global__ __launch_bounds__(64) void rnn_dot2_kernel(
    const float* __restrict__ x,     // [B, T, IN]
    const float* __restrict__ W_ih,  // [H, IN]
    const float* __restrict__ W_hh,  // [H, H]
    const float* __restrict__ b_ih,  // [H]
    const float* __restrict__ b_hh,  // [H]
    const float* __restrict__ fc_w,  // [1, H]
    const float* __restrict__ fc_b,  // [1]
    float* __restrict__ out)         // [B, 1]
{
    __shared__ __align__(16) float xs[2 * BUFSZ];   // 8.3 KB double-buffered x

    const int lane = (int)threadIdx.x;   // 0..63
    const int j    = lane & 15;          // hidden unit
    const int g    = lane >> 4;          // element within wave (0..3)
    const int b0   = (int)blockIdx.x * NE;
    const float C2 = 2.8853900817779268f;   // 2*log2(e)

    // --- PAIR calibration: run the EXACT runtime DPP tree on j and ror1(j).
    // A[t]/Bv[t] = source units landing in packed slot t's (lo, hi) halves.
    uint32_t A[8], Bv[8];
    {
        const uint32_t j0 = (uint32_t)j;
        const uint32_t j1 = ROR16(j0, 1);       // same op as runtime rn
        A[0] = j0;            Bv[0] = j1;
        A[4] = ROR16(A[0],8); Bv[4] = ROR16(Bv[0],8);
        A[2] = ROR16(A[0],4); Bv[2] = ROR16(Bv[0],4);
        A[6] = ROR16(A[4],4); Bv[6] = ROR16(Bv[4],4);
        A[1] = ROR16(A[0],2); Bv[1] = ROR16(Bv[0],2);
        A[3] = ROR16(A[2],2); Bv[3] = ROR16(Bv[2],2);
        A[5] = ROR16(A[4],2); Bv[5] = ROR16(Bv[4],2);
        A[7] = ROR16(A[6],2); Bv[7] = ROR16(Bv[6],2);
    }

    // --- packed weights (hi + lo residual), pre-permuted to slot order.
    uint32_t wh[8], wl[8];
    float wsum = 0.0f;
#pragma unroll
    for (int t = 0; t < 8; ++t) {
        const float wa = -2.0f * C2 * W_hh[j * RNN_H + (int)A[t]];
        const float wb = -2.0f * C2 * W_hh[j * RNN_H + (int)Bv[t]];
        const __fp16 wah = (__fp16)wa, wbh = (__fp16)wb;
        const __fp16 wal = (__fp16)(wa - (float)wah), wbl = (__fp16)(wb - (float)wbh);
        H2U h1; h1.h[0] = wah; h1.h[1] = wbh; wh[t] = h1.u;
        H2U h2; h2.h[0] = wal; h2.h[1] = wbl; wl[t] = h2.u;
        wsum += (float)wah + (float)wal + (float)wbh + (float)wbl;
    }
    // bias fold consistent with the represented weights: S = ... - 0.5*sum(w_eff)
    const float bias_l = C2 * (b_ih[j] + b_hh[j]) - 0.5f * wsum;

    float wih[RNN_IN];
#pragma unroll
    for (int i = 0; i < RNN_IN; i += 4) {
        const float4 w = *(const float4*)(W_ih + j * RNN_IN + i);
        wih[i] = C2 * w.x; wih[i+1] = C2 * w.y; wih[i+2] = C2 * w.z; wih[i+3] = C2 * w.w;
    }

    // prologue: tile 0 -> buffer 0
    stage(x, xs, b0, 0, lane);
    __syncthreads();

    float rv = 0.5f;   // r-state for h0 = 0  (h = 1 - 2r)

    for (int tile = 0; tile < NTILE; ++tile) {
        const int cur = tile & 1;

        // ---- OFF-CHAIN: x-projection for the whole tile (f32, exact).
        // 16-lane broadcast reads; 32 VGPRs, static indexing.
        const float* xg = xs + cur * BUFSZ + g * XROW;
        float xp[TC];
#pragma unroll
        for (int tt = 0; tt < TC; ++tt) {
            const float4 xa = *(const float4*)(xg + tt * 8);
            const float4 xb = *(const float4*)(xg + tt * 8 + 4);
            float t0 = fmaf(wih[0], xa.x, bias_l);
            t0 = fmaf(wih[1], xa.y, t0);
            t0 = fmaf(wih[2], xa.z, t0);
            t0 = fmaf(wih[3], xa.w, t0);
            float t1 = wih[4] * xb.x;
            t1 = fmaf(wih[5], xb.y, t1);
            t1 = fmaf(wih[6], xb.z, t1);
            t1 = fmaf(wih[7], xb.w, t1);
            xp[tt] = t0 + t1;
        }

        // issue next tile's async staging; drained by the end-of-tile barrier
        if (tile + 1 < NTILE)
            stage(x, xs + (cur ^ 1) * BUFSZ, b0, (tile + 1) * TC, lane);

        // ---- 32 recurrence steps. Chain: ror1 -> pkh -> 3-DPP -> 4 dot2
        // -> add -> exp2 -> add -> rcp. Residual dot2 chains join at the adds.
#pragma unroll
        for (int tt = 0; tt < TC; ++tt) {
            const uint32_t rb = __float_as_uint(rv);
            const uint32_t rn = ROR16(rb, 1);
            const uint32_t p0 = pkh(rv, __uint_as_float(rn));
            const uint32_t p4 = ROR16(p0, 8);
            const uint32_t p2 = ROR16(p0, 4);
            const uint32_t p6 = ROR16(p4, 4);
            const uint32_t p1 = ROR16(p0, 2);
            const uint32_t p3 = ROR16(p2, 2);
            const uint32_t p5 = ROR16(p4, 2);
            const uint32_t p7 = ROR16(p6, 2);

            // 4 chains of 4 dot2, ordered by packed-value availability
            float c0 = fdot2f(wh[0], p0, xp[tt]);
            c0 = fdot2f(wh[4], p4, c0);
            c0 = fdot2f(wh[2], p2, c0);
            c0 = fdot2f(wh[1], p1, c0);

            float c1 = fdot2f(wh[6], p6, 0.0f);
            c1 = fdot2f(wh[3], p3, c1);
            c1 = fdot2f(wh[5], p5, c1);
            c1 = fdot2f(wh[7], p7, c1);

            float c2 = fdot2f(wl[0], p0, 0.0f);   // W_lo residual compensation
            c2 = fdot2f(wl[4], p4, c2);
            c2 = fdot2f(wl[2], p2, c2);
            c2 = fdot2f(wl[3], p3, c2);

            float c3 = fdot2f(wl[6], p6, 0.0f);
            c3 = fdot2f(wl[1], p1, c3);
            c3 = fdot2f(wl[5], p5, c3);
            c3 = fdot2f(wl[7], p7, c3);

            const float s = (c0 + c1) + (c2 + c3);

            // r = 1/(exp2(S)+1); saturates correctly at +/-inf
            const float e = __builtin_amdgcn_exp2f(s);
            rv = __builtin_amdgcn_rcpf(e + 1.0f);
        }
        __syncthreads();   // drains next-tile staging + fences LDS reuse
    }

    // ---- epilogue: h = 1 - 2r; out[b] = sum_j fc_w[j]*h_j + fc_b
    const float h = fmaf(-2.0f, rv, 1.0f);
    float vsum = h * fc_w[j];
    vsum += __shfl_xor(vsum, 1);
    vsum += __shfl_xor(vsum, 2);
    vsum += __shfl_xor(vsum, 4);
    vsum += __shfl_xor(vsum, 8);
    if (j == 0) out[b0 + g] = vsum + fc_b[0];
}

extern "C" void kernel_launch(void* const* d_in, const int* in_sizes, int n_in,
                              void* d_out, int out_size, void* d_ws, size_t ws_size,
                              hipStream_t stream)
{
    const float* x    = (const float*)d_in[0];
    const float* W_ih = (const float*)d_in[1];
    const float* W_hh = (const float*)d_in[2];
    const float* b_ih = (const float*)d_in[3];
    const float* b_hh = (const float*)d_in[4];
    const float* fc_w = (const float*)d_in[5];
    const float* fc_b = (const float*)d_in[6];
    float* out = (float*)d_out;

    dim3 grid(RNN_B / NE);   // 2048 blocks x 64 threads (2 waves/SIMD)
    dim3 block(64);
    rnn_dot2_kernel<<<grid, block, 0, stream>>>(x, W_ih, W_hh, b_ih, b_hh, fc_w, fc_b, out);
}